// Round 1
// baseline (565.478 us; speedup 1.0000x reference)
//
#include <hip/hip_runtime.h>
#include <hip/hip_bf16.h>

#define B_DIM   8192
#define FDIM    2048
#define S_DIM   10000
#define D_DIM   100
#define E_NUM   500000
#define ETA     0.01f

#define DPAD    112          // 7 tiles of 16
#define NT      7            // n-tiles per block
#define KSTEPS  313          // ceil(10000/32); S_pad = 10016
#define KBLK    1252         // 10016/8 k-blocks in A_sw

typedef float  f32x4  __attribute__((ext_vector_type(4)));
typedef short  s16x8  __attribute__((ext_vector_type(8)));
typedef __bf16 bf16x8 __attribute__((ext_vector_type(8)));

__device__ inline unsigned short f2bf_bits(float x) {
    unsigned int u = __float_as_uint(x);
    unsigned int r = u + 0x7FFFu + ((u >> 16) & 1u);   // RNE
    return (unsigned short)(r >> 16);
}

// ---------------- scatter edge weights into A[d][s] (fp32) ----------------
__global__ void scatter_kernel(const float* __restrict__ ew,
                               const int* __restrict__ esrc,
                               const int* __restrict__ edst,
                               float* __restrict__ A) {
    int e = blockIdx.x * 256 + threadIdx.x;
    if (e < E_NUM) {
        atomicAdd(&A[(size_t)esrc[e] * S_DIM + edst[e]], ew[e]);
    }
}

// ---- transpose+pad+bf16+swizzle: A[d][s] -> Asw[((s/8)*112 + d)*8 + s%8] ----
__global__ void build_asw_kernel(const float* __restrict__ A,
                                 unsigned short* __restrict__ Asw) {
    int t = blockIdx.x * 256 + threadIdx.x;   // 0 .. 1,121,791  (= KBLK*112*8)
    int kb  = t / 896;                        // 896 = 112*8
    int rem = t - kb * 896;
    int d   = rem >> 3;
    int s   = kb * 8 + (rem & 7);
    float v = (d < D_DIM && s < S_DIM) ? A[d * S_DIM + s] : 0.f;
    Asw[t] = f2bf_bits(v);
}

// ---------------- per-row L2 norm of grad_output ----------------
__global__ void norm_kernel(const float* __restrict__ go, float* __restrict__ g) {
    int wave = threadIdx.x >> 6;
    int lane = threadIdx.x & 63;
    int row  = blockIdx.x * 4 + wave;
    const f32x4* p = (const f32x4*)(go + (size_t)row * FDIM);
    float s = 0.f;
#pragma unroll
    for (int j = 0; j < 8; ++j) {
        f32x4 v = __builtin_nontemporal_load(p + lane + 64 * j);
        s += v[0]*v[0] + v[1]*v[1] + v[2]*v[2] + v[3]*v[3];
    }
#pragma unroll
    for (int off = 32; off; off >>= 1) s += __shfl_xor(s, off);
    if (lane == 0) g[row] = sqrtf(s);
}

// ---------------- GEMM: out[i][d] = ETA*g[i]*sum_s sims[i][s]*A[d][s] ----------------
__global__ __launch_bounds__(512, 4)
void gemm_kernel(const float* __restrict__ sims,
                 const unsigned short* __restrict__ Asw,
                 const float* __restrict__ g,
                 float* __restrict__ out) {
    __shared__ float red[8][64][29];          // +29 stride: bank-conflict-free
    const int tid  = threadIdx.x;
    const int wave = tid >> 6;
    const int lane = tid & 63;
    const int lhi  = lane >> 4;               // 0..3
    const int llo  = lane & 15;               // 0..15
    const int i0   = blockIdx.x * 16;

    const float* srow = sims + (size_t)(i0 + llo) * S_DIM;

    f32x4 acc[NT];
#pragma unroll
    for (int n = 0; n < NT; ++n) acc[n] = 0.f;

    for (int t = wave; t < KSTEPS; t += 8) {
        const int k0 = t * 32;
        const int kl = k0 + 8 * lhi;          // this lane's first k (8 consecutive)

        f32x4 f0, f1;
        if (kl < S_DIM) {
            const f32x4* p = (const f32x4*)(srow + kl);
            f0 = __builtin_nontemporal_load(p);
            f1 = __builtin_nontemporal_load(p + 1);
        } else {
            f0 = 0.f; f1 = 0.f;
        }
        bf16x8 abf;
        abf[0] = (__bf16)f0[0]; abf[1] = (__bf16)f0[1];
        abf[2] = (__bf16)f0[2]; abf[3] = (__bf16)f0[3];
        abf[4] = (__bf16)f1[0]; abf[5] = (__bf16)f1[1];
        abf[6] = (__bf16)f1[2]; abf[7] = (__bf16)f1[3];
        s16x8 a = __builtin_bit_cast(s16x8, abf);

        // B fragments: 8 contiguous bf16 per lane, pre-swizzled layout
        const unsigned short* bbase = Asw + ((size_t)(4 * t + lhi) * DPAD + llo) * 8;
#pragma unroll
        for (int n = 0; n < NT; ++n) {
            s16x8 b = *(const s16x8*)(bbase + n * 128);   // 16 cols * 8 = 128 ushorts
            acc[n] = __builtin_amdgcn_mfma_f32_16x16x32_bf16(a, b, acc[n], 0, 0, 0);
        }
    }

    // cross-wave reduction of K-partials
#pragma unroll
    for (int n = 0; n < NT; ++n)
#pragma unroll
        for (int r = 0; r < 4; ++r)
            red[wave][lane][n * 4 + r] = acc[n][r];
    __syncthreads();

    if (wave == 0) {
        float gi[4];
#pragma unroll
        for (int r = 0; r < 4; ++r)
            gi[r] = ETA * g[i0 + lhi * 4 + r];
#pragma unroll
        for (int n = 0; n < NT; ++n) {
            int col = n * 16 + llo;
#pragma unroll
            for (int r = 0; r < 4; ++r) {
                float v = 0.f;
#pragma unroll
                for (int w = 0; w < 8; ++w) v += red[w][lane][n * 4 + r];
                if (col < D_DIM) {
                    int row = i0 + lhi * 4 + r;
                    out[row * D_DIM + col] = gi[r] * v;
                }
            }
        }
    }
}

extern "C" void kernel_launch(void* const* d_in, const int* in_sizes, int n_in,
                              void* d_out, int out_size, void* d_ws, size_t ws_size,
                              hipStream_t stream) {
    const float* grad = (const float*)d_in[0];   // [B, FDIM]
    const float* sims = (const float*)d_in[1];   // [B, S]
    const float* ew   = (const float*)d_in[2];   // [E]
    const int*   esrc = (const int*)d_in[3];     // [E]
    const int*   edst = (const int*)d_in[4];     // [E]
    float* out = (float*)d_out;                  // [B, D]

    char* ws = (char*)d_ws;
    float*          A   = (float*)ws;                               // 4,000,000 B
    unsigned short* Asw = (unsigned short*)(ws + 4000000);          // 2,243,584 B
    float*          g   = (float*)(ws + 4000000 + 2243584);         // 32,768 B

    hipMemsetAsync(A, 0, (size_t)D_DIM * S_DIM * sizeof(float), stream);

    scatter_kernel  <<<(E_NUM + 255) / 256, 256, 0, stream>>>(ew, esrc, edst, A);
    build_asw_kernel<<<(KBLK * DPAD * 8) / 256, 256, 0, stream>>>(A, Asw);
    norm_kernel     <<<B_DIM / 4, 256, 0, stream>>>(grad, g);
    gemm_kernel     <<<B_DIM / 16, 512, 0, stream>>>(sims, Asw, g, out);
}

// Round 2
// 551.769 us; speedup vs baseline: 1.0248x; 1.0248x over previous
//
#include <hip/hip_runtime.h>
#include <hip/hip_bf16.h>

#define B_DIM   8192
#define FDIM    2048
#define S_DIM   10000
#define D_DIM   100
#define E_NUM   500000
#define ETA     0.01f

#define DPAD    112          // 7 tiles of 16
#define NT      7            // n-tiles per block
#define KSTEPS  313          // ceil(10000/32); S_pad = 10016
#define KBLK    1252         // 10016/8 k-blocks in A_sw

typedef float  f32x4  __attribute__((ext_vector_type(4)));
typedef short  s16x8  __attribute__((ext_vector_type(8)));
typedef __bf16 bf16x8 __attribute__((ext_vector_type(8)));

__device__ inline unsigned short f2bf_bits(float x) {
    unsigned int u = __float_as_uint(x);
    unsigned int r = u + 0x7FFFu + ((u >> 16) & 1u);   // RNE
    return (unsigned short)(r >> 16);
}

// ---------------- scatter edge weights into A[d][s] (fp32) ----------------
__global__ void scatter_kernel(const float* __restrict__ ew,
                               const int* __restrict__ esrc,
                               const int* __restrict__ edst,
                               float* __restrict__ A) {
    int e = blockIdx.x * 256 + threadIdx.x;
    if (e < E_NUM) {
        atomicAdd(&A[(size_t)esrc[e] * S_DIM + edst[e]], ew[e]);
    }
}

// ---- transpose+pad+bf16+swizzle: A[d][s] -> Asw[((s/8)*112 + d)*8 + s%8] ----
__global__ void build_asw_kernel(const float* __restrict__ A,
                                 unsigned short* __restrict__ Asw) {
    int t = blockIdx.x * 256 + threadIdx.x;   // 0 .. 1,121,791  (= KBLK*112*8)
    int kb  = t / 896;                        // 896 = 112*8
    int rem = t - kb * 896;
    int d   = rem >> 3;
    int s   = kb * 8 + (rem & 7);
    float v = (d < D_DIM && s < S_DIM) ? A[d * S_DIM + s] : 0.f;
    Asw[t] = f2bf_bits(v);
}

// ---------------- per-row L2 norm of grad_output ----------------
__global__ void norm_kernel(const float* __restrict__ go, float* __restrict__ g) {
    int wave = threadIdx.x >> 6;
    int lane = threadIdx.x & 63;
    int row  = blockIdx.x * 4 + wave;
    const f32x4* p = (const f32x4*)(go + (size_t)row * FDIM);
    float s = 0.f;
#pragma unroll
    for (int j = 0; j < 8; ++j) {
        f32x4 v = __builtin_nontemporal_load(p + lane + 64 * j);
        s += v[0]*v[0] + v[1]*v[1] + v[2]*v[2] + v[3]*v[3];
    }
#pragma unroll
    for (int off = 32; off; off >>= 1) s += __shfl_xor(s, off);
    if (lane == 0) g[row] = sqrtf(s);
}

// ---------------- GEMM: out[i][d] = ETA*g[i]*sum_s sims[i][s]*A[d][s] ----------------
__device__ inline s16x8 cvt_a(f32x4 f0, f32x4 f1) {
    bf16x8 abf;
    abf[0] = (__bf16)f0[0]; abf[1] = (__bf16)f0[1];
    abf[2] = (__bf16)f0[2]; abf[3] = (__bf16)f0[3];
    abf[4] = (__bf16)f1[0]; abf[5] = (__bf16)f1[1];
    abf[6] = (__bf16)f1[2]; abf[7] = (__bf16)f1[3];
    return __builtin_bit_cast(s16x8, abf);
}

__global__ __launch_bounds__(512, 4)
void gemm_kernel(const float* __restrict__ sims,
                 const unsigned short* __restrict__ Asw,
                 const float* __restrict__ g,
                 float* __restrict__ out) {
    __shared__ float red[8][64][29];          // odd stride: bank-conflict-free
    const int tid  = threadIdx.x;
    const int wave = tid >> 6;
    const int lane = tid & 63;
    const int lhi  = lane >> 4;               // 0..3 -> k-subchunk
    const int llo  = lane & 15;               // 0..15 -> row (A) / col (B)
    const int i0   = blockIdx.x * 16;

    const float* srow = sims + (size_t)(i0 + llo) * S_DIM + 8 * lhi;

    f32x4 acc[NT];
#pragma unroll
    for (int n = 0; n < NT; ++n) acc[n] = 0.f;

    // ---- software-pipelined main loop: t in {wave, wave+8, ...} < 312,
    //      all guard-free (k max = 311*32+24+8 = 9984 <= 10000, loads end at 9992? no:
    //      kl = t*32 + 8*lhi <= 311*32+24 = 9976; reads floats [9976,9984) and [9984,9992) < 10000. safe)
    int t = wave;
    f32x4 f0, f1;
    {
        const f32x4* p = (const f32x4*)(srow + t * 32);
        f0 = p[0]; f1 = p[1];
    }
    for (; t < 312; t += 8) {
        // prefetch next iteration's sims chunk (static regs, no arrays)
        f32x4 n0, n1;
        n0 = 0.f; n1 = 0.f;
        const int tn = t + 8;
        if (tn < 312) {
            const f32x4* p = (const f32x4*)(srow + tn * 32);
            n0 = p[0]; n1 = p[1];
        }

        // B fragments for current t: issue loads before conversion VALU
        const unsigned short* bbase = Asw + ((size_t)(4 * t + lhi) * DPAD + llo) * 8;
        s16x8 b0 = *(const s16x8*)(bbase);
        s16x8 b1 = *(const s16x8*)(bbase + 128);
        s16x8 b2 = *(const s16x8*)(bbase + 256);
        s16x8 b3 = *(const s16x8*)(bbase + 384);
        s16x8 b4 = *(const s16x8*)(bbase + 512);
        s16x8 b5 = *(const s16x8*)(bbase + 640);
        s16x8 b6 = *(const s16x8*)(bbase + 768);

        s16x8 a = cvt_a(f0, f1);
        acc[0] = __builtin_amdgcn_mfma_f32_16x16x32_bf16(a, b0, acc[0], 0, 0, 0);
        acc[1] = __builtin_amdgcn_mfma_f32_16x16x32_bf16(a, b1, acc[1], 0, 0, 0);
        acc[2] = __builtin_amdgcn_mfma_f32_16x16x32_bf16(a, b2, acc[2], 0, 0, 0);
        acc[3] = __builtin_amdgcn_mfma_f32_16x16x32_bf16(a, b3, acc[3], 0, 0, 0);
        acc[4] = __builtin_amdgcn_mfma_f32_16x16x32_bf16(a, b4, acc[4], 0, 0, 0);
        acc[5] = __builtin_amdgcn_mfma_f32_16x16x32_bf16(a, b5, acc[5], 0, 0, 0);
        acc[6] = __builtin_amdgcn_mfma_f32_16x16x32_bf16(a, b6, acc[6], 0, 0, 0);

        f0 = n0; f1 = n1;
    }

    // ---- tail: t = 312 (only wave 0 reaches it). k0 = 9984; lhi 0/1 in-bounds, 2/3 are pad.
    if (wave == 0) {
        f32x4 t0, t1;
        t0 = 0.f; t1 = 0.f;
        if (lhi < 2) {
            const f32x4* p = (const f32x4*)(srow + 312 * 32);
            t0 = p[0]; t1 = p[1];
        }
        const unsigned short* bbase = Asw + ((size_t)(4 * 312 + lhi) * DPAD + llo) * 8;
        s16x8 a = cvt_a(t0, t1);
#pragma unroll
        for (int n = 0; n < NT; ++n) {
            s16x8 b = *(const s16x8*)(bbase + n * 128);
            acc[n] = __builtin_amdgcn_mfma_f32_16x16x32_bf16(a, b, acc[n], 0, 0, 0);
        }
    }

    // cross-wave reduction of K-partials
#pragma unroll
    for (int n = 0; n < NT; ++n)
#pragma unroll
        for (int r = 0; r < 4; ++r)
            red[wave][lane][n * 4 + r] = acc[n][r];
    __syncthreads();

    if (wave == 0) {
        float gi[4];
#pragma unroll
        for (int r = 0; r < 4; ++r)
            gi[r] = ETA * g[i0 + lhi * 4 + r];
#pragma unroll
        for (int n = 0; n < NT; ++n) {
            int col = n * 16 + llo;
#pragma unroll
            for (int r = 0; r < 4; ++r) {
                float v = 0.f;
#pragma unroll
                for (int w = 0; w < 8; ++w) v += red[w][lane][n * 4 + r];
                if (col < D_DIM) {
                    int row = i0 + lhi * 4 + r;
                    out[row * D_DIM + col] = gi[r] * v;
                }
            }
        }
    }
}

extern "C" void kernel_launch(void* const* d_in, const int* in_sizes, int n_in,
                              void* d_out, int out_size, void* d_ws, size_t ws_size,
                              hipStream_t stream) {
    const float* grad = (const float*)d_in[0];   // [B, FDIM]
    const float* sims = (const float*)d_in[1];   // [B, S]
    const float* ew   = (const float*)d_in[2];   // [E]
    const int*   esrc = (const int*)d_in[3];     // [E]
    const int*   edst = (const int*)d_in[4];     // [E]
    float* out = (float*)d_out;                  // [B, D]

    char* ws = (char*)d_ws;
    float*          A   = (float*)ws;                               // 4,000,000 B
    unsigned short* Asw = (unsigned short*)(ws + 4000000);          // 2,243,584 B
    float*          g   = (float*)(ws + 4000000 + 2243584);         // 32,768 B

    hipMemsetAsync(A, 0, (size_t)D_DIM * S_DIM * sizeof(float), stream);

    scatter_kernel  <<<(E_NUM + 255) / 256, 256, 0, stream>>>(ew, esrc, edst, A);
    build_asw_kernel<<<(KBLK * DPAD * 8) / 256, 256, 0, stream>>>(A, Asw);
    norm_kernel     <<<B_DIM / 4, 256, 0, stream>>>(grad, g);
    gemm_kernel     <<<B_DIM / 16, 512, 0, stream>>>(sims, Asw, g, out);
}

// Round 3
// 517.179 us; speedup vs baseline: 1.0934x; 1.0669x over previous
//
#include <hip/hip_runtime.h>
#include <hip/hip_bf16.h>

#define B_DIM   8192
#define FDIM    2048
#define S_DIM   10000
#define D_DIM   100
#define E_NUM   500000
#define ETA     0.01f

#define DPAD    112          // 7 tiles of 16 disease-cols
#define NT      7            // n-tiles
#define KSTEPS  313          // S padded to 10016 = 313*32
#define KSPLIT  8            // K split across blocks
#define MROWS   128          // rows per block (8 waves x 16)
#define KBLK    1252         // 10016/8 8-elem k-blocks in Asw

typedef float  f32x4  __attribute__((ext_vector_type(4)));
typedef short  s16x8  __attribute__((ext_vector_type(8)));
typedef __bf16 bf16x8 __attribute__((ext_vector_type(8)));

__device__ inline unsigned short f2bf_bits(float x) {
    unsigned int u = __float_as_uint(x);
    unsigned int r = u + 0x7FFFu + ((u >> 16) & 1u);   // RNE
    return (unsigned short)(r >> 16);
}

// ---------------- scatter edge weights into A[d][s] (fp32) ----------------
__global__ void scatter_kernel(const float* __restrict__ ew,
                               const int* __restrict__ esrc,
                               const int* __restrict__ edst,
                               float* __restrict__ A) {
    int e = blockIdx.x * 256 + threadIdx.x;
    if (e < E_NUM) {
        atomicAdd(&A[(size_t)esrc[e] * S_DIM + edst[e]], ew[e]);
    }
}

// ---- transpose+pad+bf16+swizzle: A[d][s] -> Asw[((s/8)*112 + d)*8 + s%8] ----
__global__ void build_asw_kernel(const float* __restrict__ A,
                                 unsigned short* __restrict__ Asw) {
    int t = blockIdx.x * 256 + threadIdx.x;   // 0 .. 1,121,791  (= KBLK*112*8)
    int kb  = t / 896;                        // 896 = 112*8
    int rem = t - kb * 896;
    int d   = rem >> 3;
    int s   = kb * 8 + (rem & 7);
    float v = (d < D_DIM && s < S_DIM) ? A[d * S_DIM + s] : 0.f;
    Asw[t] = f2bf_bits(v);
}

// ---------------- per-row L2 norm of grad_output ----------------
__global__ void norm_kernel(const float* __restrict__ go, float* __restrict__ g) {
    int wave = threadIdx.x >> 6;
    int lane = threadIdx.x & 63;
    int row  = blockIdx.x * 4 + wave;
    const f32x4* p = (const f32x4*)(go + (size_t)row * FDIM);
    float s = 0.f;
#pragma unroll
    for (int j = 0; j < 8; ++j) {
        f32x4 v = __builtin_nontemporal_load(p + lane + 64 * j);
        s += v[0]*v[0] + v[1]*v[1] + v[2]*v[2] + v[3]*v[3];
    }
#pragma unroll
    for (int off = 32; off; off >>= 1) s += __shfl_xor(s, off);
    if (lane == 0) g[row] = sqrtf(s);
}

// ---------------- GEMM with block-level K-split + LDS-shared B ----------------
__device__ inline s16x8 cvt_a(f32x4 f0, f32x4 f1) {
    bf16x8 abf;
    abf[0] = (__bf16)f0[0]; abf[1] = (__bf16)f0[1];
    abf[2] = (__bf16)f0[2]; abf[3] = (__bf16)f0[3];
    abf[4] = (__bf16)f1[0]; abf[5] = (__bf16)f1[1];
    abf[6] = (__bf16)f1[2]; abf[7] = (__bf16)f1[3];
    return __builtin_bit_cast(s16x8, abf);
}

// grid = 64 rowblocks * 8 ksplits; kb = blockIdx&7 so each XCD pins one 280KB B-chunk in L2
__global__ __launch_bounds__(512, 4)
void gemm_kernel(const float* __restrict__ sims,
                 const unsigned short* __restrict__ Asw,
                 float* __restrict__ part) {
    __shared__ unsigned short buf[2][3584];   // 2 x 7168 B double-buffered B slab
    const int tid  = threadIdx.x;
    const int wave = tid >> 6;
    const int lane = tid & 63;
    const int lhi  = lane >> 4;               // k-subchunk 0..3
    const int llo  = lane & 15;               // A-row / B-col within tile

    const int kb = blockIdx.x & 7;
    const int rb = blockIdx.x >> 3;
    const int t0 = (KSTEPS * kb) >> 3;        // this block's K-step range
    const int t1 = (KSTEPS * (kb + 1)) >> 3;
    const int nsteps = t1 - t0;

    const int row0 = rb * MROWS + wave * 16;  // this wave's 16 rows
    const float* srow = sims + (size_t)(row0 + llo) * S_DIM + 8 * lhi;

    f32x4 acc[NT];
#pragma unroll
    for (int n = 0; n < NT; ++n) acc[n] = 0.f;

    // prologue: stage slab t0, load sims t0 (t0 <= 273, always in-bounds)
    if (tid < 448) {
        s16x8 v = *(const s16x8*)(Asw + (size_t)t0 * 3584 + tid * 8);
        *(s16x8*)&buf[0][tid * 8] = v;
    }
    f32x4 f0, f1;
    {
        const f32x4* p = (const f32x4*)(srow + t0 * 32);
        f0 = p[0]; f1 = p[1];
    }
    __syncthreads();

    for (int i = 0; i < nsteps; ++i) {
        const int t = t0 + i;
        const int cur = i & 1;

        // stage next slab into other buffer (7168 B, 448 threads x 16 B)
        if (i + 1 < nsteps && tid < 448) {
            s16x8 v = *(const s16x8*)(Asw + (size_t)(t + 1) * 3584 + tid * 8);
            *(s16x8*)&buf[cur ^ 1][tid * 8] = v;
        }

        // prefetch next sims chunk (guard: last step's lhi>=2 is past row end; B is 0 there)
        f32x4 n0 = 0.f, n1 = 0.f;
        {
            const int kn = (t + 1) * 32 + 8 * lhi;
            if (i + 1 < nsteps && kn <= S_DIM - 8) {
                const f32x4* p = (const f32x4*)(srow + (size_t)(t + 1) * 32);
                n0 = p[0]; n1 = p[1];
            }
        }

        // B fragments from LDS: base + n*256B immediate offsets
        const unsigned short* bb = &buf[cur][lhi * 896 + llo * 8];
        s16x8 b0 = *(const s16x8*)(bb);
        s16x8 b1 = *(const s16x8*)(bb + 128);
        s16x8 b2 = *(const s16x8*)(bb + 256);
        s16x8 b3 = *(const s16x8*)(bb + 384);
        s16x8 b4 = *(const s16x8*)(bb + 512);
        s16x8 b5 = *(const s16x8*)(bb + 640);
        s16x8 b6 = *(const s16x8*)(bb + 768);

        s16x8 a = cvt_a(f0, f1);
        acc[0] = __builtin_amdgcn_mfma_f32_16x16x32_bf16(a, b0, acc[0], 0, 0, 0);
        acc[1] = __builtin_amdgcn_mfma_f32_16x16x32_bf16(a, b1, acc[1], 0, 0, 0);
        acc[2] = __builtin_amdgcn_mfma_f32_16x16x32_bf16(a, b2, acc[2], 0, 0, 0);
        acc[3] = __builtin_amdgcn_mfma_f32_16x16x32_bf16(a, b3, acc[3], 0, 0, 0);
        acc[4] = __builtin_amdgcn_mfma_f32_16x16x32_bf16(a, b4, acc[4], 0, 0, 0);
        acc[5] = __builtin_amdgcn_mfma_f32_16x16x32_bf16(a, b5, acc[5], 0, 0, 0);
        acc[6] = __builtin_amdgcn_mfma_f32_16x16x32_bf16(a, b6, acc[6], 0, 0, 0);

        f0 = n0; f1 = n1;
        __syncthreads();
    }

    // epilogue: write fp32 partials (each slot written by exactly one block)
    float* pslab = part + (size_t)kb * (B_DIM * D_DIM);
    const int rbase = row0 + lhi * 4;
#pragma unroll
    for (int n = 0; n < NT; ++n) {
        const int col = n * 16 + llo;
        if (col < D_DIM) {
#pragma unroll
            for (int r = 0; r < 4; ++r)
                pslab[(size_t)(rbase + r) * D_DIM + col] = acc[n][r];
        }
    }
}

// ---------------- final: out[i][d] = ETA*g[i]*sum_kb part[kb][i][d] ----------------
__global__ void reduce_kernel(const float* __restrict__ part,
                              const float* __restrict__ g,
                              float* __restrict__ out) {
    int idx = blockIdx.x * 256 + threadIdx.x;
    if (idx < B_DIM * D_DIM) {
        float s = 0.f;
#pragma unroll
        for (int kb = 0; kb < KSPLIT; ++kb)
            s += part[(size_t)kb * (B_DIM * D_DIM) + idx];
        int i = idx / D_DIM;
        out[idx] = ETA * g[i] * s;
    }
}

extern "C" void kernel_launch(void* const* d_in, const int* in_sizes, int n_in,
                              void* d_out, int out_size, void* d_ws, size_t ws_size,
                              hipStream_t stream) {
    const float* grad = (const float*)d_in[0];   // [B, FDIM]
    const float* sims = (const float*)d_in[1];   // [B, S]
    const float* ew   = (const float*)d_in[2];   // [E]
    const int*   esrc = (const int*)d_in[3];     // [E]
    const int*   edst = (const int*)d_in[4];     // [E]
    float* out = (float*)d_out;                  // [B, D]

    char* ws = (char*)d_ws;
    float*          A    = (float*)(ws);                    // 4,000,000 B
    unsigned short* Asw  = (unsigned short*)(ws + (4 << 20));   // 2,243,584 B
    float*          g    = (float*)(ws + (7 << 20));        // 32,768 B
    float*          part = (float*)(ws + (8 << 20));        // 26,214,400 B

    hipMemsetAsync(A, 0, (size_t)D_DIM * S_DIM * sizeof(float), stream);

    scatter_kernel  <<<(E_NUM + 255) / 256, 256, 0, stream>>>(ew, esrc, edst, A);
    build_asw_kernel<<<(KBLK * DPAD * 8) / 256, 256, 0, stream>>>(A, Asw);
    norm_kernel     <<<B_DIM / 4, 256, 0, stream>>>(grad, g);
    gemm_kernel     <<<64 * KSPLIT, 512, 0, stream>>>(sims, Asw, part);
    reduce_kernel   <<<(B_DIM * D_DIM + 255) / 256, 256, 0, stream>>>(part, g, out);
}